// Round 2
// baseline (339.100 us; speedup 1.0000x reference)
//
#include <hip/hip_runtime.h>

#define B_ 2
#define S_ 2048
#define H_ 16
#define D_ 64
#define QBLK 64
#define KBLK 64

typedef _Float16 f16x8 __attribute__((ext_vector_type(8)));
typedef float f32x4 __attribute__((ext_vector_type(4)));

// ---------------- projection kernel ----------------
// grid = ((B*S*H)/8, 3), block = 512
// out layout: [B, H, S, D] f16. q is pre-scaled by 1/sqrt(D)=0.125.
__global__ __launch_bounds__(512) void proj_kernel(
    const float* __restrict__ query, const float* __restrict__ key,
    const float* __restrict__ value,
    const float* __restrict__ Wq, const float* __restrict__ bq,
    const float* __restrict__ Wk, const float* __restrict__ bk,
    const float* __restrict__ Wv, const float* __restrict__ bv,
    _Float16* __restrict__ qo, _Float16* __restrict__ ko, _Float16* __restrict__ vo)
{
    __shared__ float Ws[64][65];   // +1 pad: no bank conflicts
    __shared__ float xs[8][64];

    const int which = blockIdx.y;
    const float* x    = which == 0 ? query : (which == 1 ? key : value);
    const float* W    = which == 0 ? Wq    : (which == 1 ? Wk  : Wv);
    const float* bias = which == 0 ? bq    : (which == 1 ? bk  : bv);
    _Float16*    out  = which == 0 ? qo    : (which == 1 ? ko  : vo);
    const float scale = which == 0 ? 0.125f : 1.0f;

    const int t = threadIdx.x;
    for (int i = t; i < 4096; i += 512) Ws[i >> 6][i & 63] = W[i];

    const long T0 = (long)blockIdx.x * 8;
    {
        int r = t >> 6, d = t & 63;
        xs[r][d] = x[(T0 + r) * 64 + d];
    }
    __syncthreads();

    const int r = t >> 6, j = t & 63;
    float acc = bias[j];
    #pragma unroll
    for (int d = 0; d < 64; ++d) acc += xs[r][d] * Ws[j][d];
    acc *= scale;

    const long T = T0 + r;
    const int b = (int)(T / (S_ * H_));
    const int rem = (int)(T % (S_ * H_));
    const int s = rem / H_;
    const int h = rem % H_;
    out[(((long)(b * H_ + h)) * S_ + s) * 64 + j] = (_Float16)acc;
}

// ---------------- flash attention kernel ----------------
// grid = (B*H, S/QBLK), block = 256 (4 waves; wave w owns q-rows [w*16, w*16+16))
__global__ __launch_bounds__(256) void attn_kernel(
    const _Float16* __restrict__ Qg, const _Float16* __restrict__ Kg,
    const _Float16* __restrict__ Vg, float* __restrict__ Og)
{
    // all tiles XOR-swizzled: byte ^= ((row&7)<<4)  (128B rows -> 8 distinct 16B slots)
    __shared__ _Float16 Kt[64 * 64];      // [key][d]
    __shared__ _Float16 Vt[64 * 64];      // [d][key]  (transposed)
    __shared__ _Float16 Pl[4][16 * 64];   // per-wave [q-row][key]

    const int bh   = blockIdx.x;
    const int qt   = blockIdx.y;
    const _Float16* Qb = Qg + (long)bh * S_ * 64;
    const _Float16* Kb = Kg + (long)bh * S_ * 64;
    const _Float16* Vb = Vg + (long)bh * S_ * 64;

    const int t    = threadIdx.x;
    const int wave = t >> 6;
    const int lane = t & 63;
    const int lg   = lane >> 4;   // 0..3
    const int lr   = lane & 15;

    // Q fragments (A-operand, 16x16x32: row = lane&15, k = 8*(lane>>4)+e contiguous)
    f16x8 qf[2];
    {
        const _Float16* qrow = Qb + ((long)(qt * QBLK + wave * 16 + lr)) * 64;
        qf[0] = *(const f16x8*)(qrow + 0 * 32 + lg * 8);
        qf[1] = *(const f16x8*)(qrow + 1 * 32 + lg * 8);
    }

    f32x4 o[4] = {};          // O accumulator, d-blocks of 16
    float m[4], l_[4];
    #pragma unroll
    for (int r = 0; r < 4; ++r) { m[r] = -1e30f; l_[r] = 0.f; }

    for (int kt = 0; kt < S_ / KBLK; ++kt) {
        __syncthreads();
        // ---- stage K tile (vectorized, swizzled) ----
        {
            const _Float16* src = Kb + (long)kt * KBLK * 64;
            #pragma unroll
            for (int idx = t; idx < 512; idx += 256) {
                int row = idx >> 3, c = idx & 7;
                uint4 v = *(const uint4*)(src + row * 64 + c * 8);
                int byte = (row * 128 + c * 16) ^ ((row & 7) << 4);
                *(uint4*)((char*)Kt + byte) = v;
            }
            // ---- stage V transposed (scalar LDS writes, swizzled) ----
            const _Float16* vsrc = Vb + (long)kt * KBLK * 64;
            #pragma unroll
            for (int idx = t; idx < 512; idx += 256) {
                int row = idx >> 3, c = idx & 7;   // key=row, d = c*8+j
                f16x8 v = *(const f16x8*)(vsrc + row * 64 + c * 8);
                #pragma unroll
                for (int j = 0; j < 8; ++j) {
                    int d = c * 8 + j;
                    int byte = (d * 128 + row * 2) ^ ((d & 7) << 4);
                    *(_Float16*)((char*)Vt + byte) = v[j];
                }
            }
        }
        __syncthreads();

        // ---- QK^T: S[qr][key], 4 key-blocks x 2 k-chunks ----
        f32x4 sc[4];
        #pragma unroll
        for (int f = 0; f < 4; ++f) {
            f32x4 a = {};
            #pragma unroll
            for (int kc = 0; kc < 2; ++kc) {
                int row = f * 16 + lr;
                int byte = (row * 128 + (kc * 32 + lg * 8) * 2) ^ ((row & 7) << 4);
                f16x8 bfr = *(const f16x8*)((const char*)Kt + byte);
                a = __builtin_amdgcn_mfma_f32_16x16x32_f16(qf[kc], bfr, a, 0, 0, 0);
            }
            sc[f] = a;
        }

        // ---- online softmax (rows live in 16-lane groups sharing lane>>4) ----
        float pm[4];
        #pragma unroll
        for (int r = 0; r < 4; ++r)
            pm[r] = fmaxf(fmaxf(sc[0][r], sc[1][r]), fmaxf(sc[2][r], sc[3][r]));
        #pragma unroll
        for (int off = 1; off < 16; off <<= 1) {
            #pragma unroll
            for (int r = 0; r < 4; ++r) pm[r] = fmaxf(pm[r], __shfl_xor(pm[r], off));
        }
        float mn[4], rs[4];
        #pragma unroll
        for (int r = 0; r < 4; ++r) {
            mn[r] = fmaxf(m[r], pm[r]);
            rs[r] = __expf(m[r] - mn[r]);
            m[r]  = mn[r];
            l_[r] *= rs[r];
        }
        #pragma unroll
        for (int db = 0; db < 4; ++db)
            #pragma unroll
            for (int r = 0; r < 4; ++r) o[db][r] *= rs[r];

        // ---- P = exp(S - m), write to wave-private LDS (swizzled) ----
        char* pbase = (char*)&Pl[wave][0];
        #pragma unroll
        for (int f = 0; f < 4; ++f) {
            #pragma unroll
            for (int r = 0; r < 4; ++r) {
                float p = __expf(sc[f][r] - mn[r]);
                l_[r] += p;
                int R = lg * 4 + r;
                int byte = (R * 128 + (f * 16 + lr) * 2) ^ ((R & 7) << 4);
                *(_Float16*)(pbase + byte) = (_Float16)p;
            }
        }

        // ---- PV: O += P @ V ----
        #pragma unroll
        for (int db = 0; db < 4; ++db) {
            #pragma unroll
            for (int kc = 0; kc < 2; ++kc) {
                int pbyte = (lr * 128 + (kc * 32 + lg * 8) * 2) ^ ((lr & 7) << 4);
                f16x8 pa = *(const f16x8*)(pbase + pbyte);
                int vrow = db * 16 + lr;
                int vbyte = (vrow * 128 + (kc * 32 + lg * 8) * 2) ^ ((vrow & 7) << 4);
                f16x8 vb = *(const f16x8*)((const char*)Vt + vbyte);
                o[db] = __builtin_amdgcn_mfma_f32_16x16x32_f16(pa, vb, o[db], 0, 0, 0);
            }
        }
    }

    // ---- epilogue: cross-lane sum of l, normalize, store fp32 ----
    #pragma unroll
    for (int off = 1; off < 16; off <<= 1) {
        #pragma unroll
        for (int r = 0; r < 4; ++r) l_[r] += __shfl_xor(l_[r], off);
    }
    float inv[4];
    #pragma unroll
    for (int r = 0; r < 4; ++r) inv[r] = 1.0f / l_[r];

    const long obase = ((long)bh * S_ + qt * QBLK + wave * 16) * 64;
    #pragma unroll
    for (int db = 0; db < 4; ++db) {
        #pragma unroll
        for (int r = 0; r < 4; ++r) {
            int R = lg * 4 + r;
            int d = db * 16 + lr;
            Og[obase + (long)R * 64 + d] = o[db][r] * inv[r];
        }
    }
}

extern "C" void kernel_launch(void* const* d_in, const int* in_sizes, int n_in,
                              void* d_out, int out_size, void* d_ws, size_t ws_size,
                              hipStream_t stream) {
    const float* query = (const float*)d_in[0];
    const float* key   = (const float*)d_in[1];
    const float* value = (const float*)d_in[2];
    const float* Wq    = (const float*)d_in[3];
    const float* bq    = (const float*)d_in[4];
    const float* Wk    = (const float*)d_in[5];
    const float* bk    = (const float*)d_in[6];
    const float* Wv    = (const float*)d_in[7];
    const float* bv    = (const float*)d_in[8];

    const size_t elems = (size_t)B_ * H_ * S_ * D_;
    _Float16* qws = (_Float16*)d_ws;
    _Float16* kws = qws + elems;
    _Float16* vws = kws + elems;

    proj_kernel<<<dim3((B_ * S_ * H_) / 8, 3), 512, 0, stream>>>(
        query, key, value, Wq, bq, Wk, bk, Wv, bv, qws, kws, vws);

    attn_kernel<<<dim3(B_ * H_, S_ / QBLK), 256, 0, stream>>>(
        qws, kws, vws, (float*)d_out);
}

// Round 4
// 233.919 us; speedup vs baseline: 1.4496x; 1.4496x over previous
//
#include <hip/hip_runtime.h>

#define B_ 2
#define S_ 2048
#define H_ 16
#define D_ 64
#define QBLK 64
#define KBLK 64

typedef _Float16 f16x8 __attribute__((ext_vector_type(8)));
typedef float f32x4 __attribute__((ext_vector_type(4)));

__device__ inline f16x8 cvt8(const float* p) {
    float4 u = *(const float4*)p, v = *(const float4*)(p + 4);
    f16x8 r;
    r[0] = (_Float16)u.x; r[1] = (_Float16)u.y; r[2] = (_Float16)u.z; r[3] = (_Float16)u.w;
    r[4] = (_Float16)v.x; r[5] = (_Float16)v.y; r[6] = (_Float16)v.z; r[7] = (_Float16)v.w;
    return r;
}

// ---------------- projection kernel (MFMA) ----------------
// grid = (S/64, B*H, 3), block = 256 (4 waves; wave w owns 16 tokens of one head)
// out layout: [B, H, S, D] f16. q pre-scaled by 0.125 (applied to acc+bias).
__global__ __launch_bounds__(256) void proj_kernel(
    const float* __restrict__ query, const float* __restrict__ key,
    const float* __restrict__ value,
    const float* __restrict__ Wq, const float* __restrict__ bq,
    const float* __restrict__ Wk, const float* __restrict__ bk,
    const float* __restrict__ Wv, const float* __restrict__ bv,
    _Float16* __restrict__ qo, _Float16* __restrict__ ko, _Float16* __restrict__ vo)
{
    const int which = blockIdx.z;
    const float* x    = which == 0 ? query : (which == 1 ? key : value);
    const float* W    = which == 0 ? Wq    : (which == 1 ? Wk  : Wv);
    const float* bias = which == 0 ? bq    : (which == 1 ? bk  : bv);
    _Float16*    out  = which == 0 ? qo    : (which == 1 ? ko  : vo);
    const float scale = which == 0 ? 0.125f : 1.0f;

    const int bh = blockIdx.y;          // b*H + h
    const int b  = bh >> 4, h = bh & 15;
    const int s0 = blockIdx.x * 64;

    const int t = threadIdx.x;
    const int wave = t >> 6, lane = t & 63;
    const int lg = lane >> 4, lr = lane & 15;

    // A fragments: token s = s0 + wave*16 + lr (same head h), k = kc*32 + lg*8 + e
    const float* xrow = x + ((long)((b * S_ + s0 + wave * 16 + lr)) * H_ + h) * 64;
    f16x8 a[2];
    a[0] = cvt8(xrow + 0 * 32 + lg * 8);
    a[1] = cvt8(xrow + 1 * 32 + lg * 8);

    // B fragments from W (row lr of each 16-col block), accumulate
    f32x4 acc[4] = {};
    #pragma unroll
    for (int jb = 0; jb < 4; ++jb) {
        #pragma unroll
        for (int kc = 0; kc < 2; ++kc) {
            f16x8 bf = cvt8(W + (jb * 16 + lr) * 64 + kc * 32 + lg * 8);
            acc[jb] = __builtin_amdgcn_mfma_f32_16x16x32_f16(a[kc], bf, acc[jb], 0, 0, 0);
        }
    }

    const long orow = (long)bh * S_ + s0 + wave * 16;
    #pragma unroll
    for (int jb = 0; jb < 4; ++jb) {
        float bj = bias[jb * 16 + lr];
        #pragma unroll
        for (int r = 0; r < 4; ++r) {
            out[(orow + lg * 4 + r) * 64 + jb * 16 + lr] =
                (_Float16)((acc[jb][r] + bj) * scale);
        }
    }
}

// ---------------- V transpose: [B,H,S,D] -> [B,H,D,S] ----------------
// grid = (S/64, B*H), block 256
__global__ __launch_bounds__(256) void transpose_v(
    const _Float16* __restrict__ in, _Float16* __restrict__ out)
{
    __shared__ _Float16 tile[64 * 64];
    const int bh = blockIdx.y;
    const int st = blockIdx.x * 64;
    const _Float16* src = in + ((long)bh * S_ + st) * 64;
    const int t = threadIdx.x;

    #pragma unroll
    for (int idx = t; idx < 512; idx += 256) {
        int s = idx >> 3, c = idx & 7;
        uint4 v = *(const uint4*)(src + s * 64 + c * 8);
        int byte = (s * 128 + c * 16) ^ ((s & 7) << 4);
        *(uint4*)((char*)tile + byte) = v;
    }
    __syncthreads();

    const int d = t >> 2, seg = t & 3;
    _Float16 pack[16];
    #pragma unroll
    for (int i = 0; i < 16; ++i) {
        int ii = (i + seg * 4) & 15;        // rotate: spreads banks across segs
        int s = seg * 16 + ii;
        int byte = (s * 128 + d * 2) ^ ((s & 7) << 4);
        pack[ii] = *(const _Float16*)((const char*)tile + byte);
    }
    _Float16* dst = out + ((long)bh * 64 + d) * S_ + st + seg * 16;
    *(uint4*)(dst)     = *(uint4*)(pack);
    *(uint4*)(dst + 8) = *(uint4*)(pack + 8);
}

// ---------------- flash attention kernel ----------------
// grid = (B*H, S/QBLK), block = 256. V input is pre-transposed [B,H,D,S].
__global__ __launch_bounds__(256) void attn_kernel(
    const _Float16* __restrict__ Qg, const _Float16* __restrict__ Kg,
    const _Float16* __restrict__ Vtg, float* __restrict__ Og)
{
    __shared__ _Float16 Kt[64 * 64];      // [key][d]   swizzled
    __shared__ _Float16 Vt[64 * 64];      // [d][key]   swizzled
    __shared__ _Float16 Pl[4][16 * 64];   // per-wave [q-row][key] swizzled

    const int bh = blockIdx.x;
    const int qt = blockIdx.y;
    const _Float16* Qb = Qg  + (long)bh * S_ * 64;
    const _Float16* Kb = Kg  + (long)bh * S_ * 64;
    const _Float16* Vb = Vtg + (long)bh * 64 * S_;   // rows = d, stride S_

    const int t = threadIdx.x;
    const int wave = t >> 6, lane = t & 63;
    const int lg = lane >> 4, lr = lane & 15;

    f16x8 qf[2];
    {
        const _Float16* qrow = Qb + ((long)(qt * QBLK + wave * 16 + lr)) * 64;
        qf[0] = *(const f16x8*)(qrow + 0 * 32 + lg * 8);
        qf[1] = *(const f16x8*)(qrow + 1 * 32 + lg * 8);
    }

    f32x4 o[4] = {};
    float m[4], l_[4];
    #pragma unroll
    for (int r = 0; r < 4; ++r) { m[r] = -1e30f; l_[r] = 0.f; }

    for (int kt = 0; kt < S_ / KBLK; ++kt) {
        __syncthreads();
        // ---- stage K tile (vectorized, swizzled) ----
        {
            const _Float16* src = Kb + (long)kt * KBLK * 64;
            #pragma unroll
            for (int idx = t; idx < 512; idx += 256) {
                int row = idx >> 3, c = idx & 7;
                uint4 v = *(const uint4*)(src + row * 64 + c * 8);
                int byte = (row * 128 + c * 16) ^ ((row & 7) << 4);
                *(uint4*)((char*)Kt + byte) = v;
            }
            // ---- stage V^T tile (vectorized, swizzled; rows are d) ----
            #pragma unroll
            for (int idx = t; idx < 512; idx += 256) {
                int row = idx >> 3, c = idx & 7;   // row = d
                uint4 v = *(const uint4*)(Vb + (long)row * S_ + kt * KBLK + c * 8);
                int byte = (row * 128 + c * 16) ^ ((row & 7) << 4);
                *(uint4*)((char*)Vt + byte) = v;
            }
        }
        __syncthreads();

        // ---- QK^T ----
        f32x4 sc[4];
        #pragma unroll
        for (int f = 0; f < 4; ++f) {
            f32x4 acc = {};
            #pragma unroll
            for (int kc = 0; kc < 2; ++kc) {
                int row = f * 16 + lr;
                int byte = (row * 128 + (kc * 32 + lg * 8) * 2) ^ ((row & 7) << 4);
                f16x8 bfr = *(const f16x8*)((const char*)Kt + byte);
                acc = __builtin_amdgcn_mfma_f32_16x16x32_f16(qf[kc], bfr, acc, 0, 0, 0);
            }
            sc[f] = acc;
        }

        // ---- online softmax ----
        float pm[4];
        #pragma unroll
        for (int r = 0; r < 4; ++r)
            pm[r] = fmaxf(fmaxf(sc[0][r], sc[1][r]), fmaxf(sc[2][r], sc[3][r]));
        #pragma unroll
        for (int off = 1; off < 16; off <<= 1) {
            #pragma unroll
            for (int r = 0; r < 4; ++r) pm[r] = fmaxf(pm[r], __shfl_xor(pm[r], off));
        }
        float mn[4], rs[4];
        #pragma unroll
        for (int r = 0; r < 4; ++r) {
            mn[r] = fmaxf(m[r], pm[r]);
            rs[r] = __expf(m[r] - mn[r]);
            m[r]  = mn[r];
            l_[r] *= rs[r];
        }
        #pragma unroll
        for (int db = 0; db < 4; ++db)
            #pragma unroll
            for (int r = 0; r < 4; ++r) o[db][r] *= rs[r];

        // ---- P = exp(S - m) -> wave-private LDS ----
        char* pbase = (char*)&Pl[wave][0];
        #pragma unroll
        for (int f = 0; f < 4; ++f) {
            #pragma unroll
            for (int r = 0; r < 4; ++r) {
                float p = __expf(sc[f][r] - mn[r]);
                l_[r] += p;
                int R = lg * 4 + r;
                int byte = (R * 128 + (f * 16 + lr) * 2) ^ ((R & 7) << 4);
                *(_Float16*)(pbase + byte) = (_Float16)p;
            }
        }

        // ---- PV (pa hoisted out of db loop) ----
        f16x8 pa[2];
        #pragma unroll
        for (int kc = 0; kc < 2; ++kc) {
            int pbyte = (lr * 128 + (kc * 32 + lg * 8) * 2) ^ ((lr & 7) << 4);
            pa[kc] = *(const f16x8*)(pbase + pbyte);
        }
        #pragma unroll
        for (int db = 0; db < 4; ++db) {
            #pragma unroll
            for (int kc = 0; kc < 2; ++kc) {
                int vrow = db * 16 + lr;
                int vbyte = (vrow * 128 + (kc * 32 + lg * 8) * 2) ^ ((vrow & 7) << 4);
                f16x8 vb = *(const f16x8*)((const char*)Vt + vbyte);
                o[db] = __builtin_amdgcn_mfma_f32_16x16x32_f16(pa[kc], vb, o[db], 0, 0, 0);
            }
        }
    }

    // ---- epilogue ----
    #pragma unroll
    for (int off = 1; off < 16; off <<= 1) {
        #pragma unroll
        for (int r = 0; r < 4; ++r) l_[r] += __shfl_xor(l_[r], off);
    }
    float inv[4];
    #pragma unroll
    for (int r = 0; r < 4; ++r) inv[r] = 1.0f / l_[r];

    const long obase = ((long)bh * S_ + qt * QBLK + wave * 16) * 64;
    #pragma unroll
    for (int db = 0; db < 4; ++db) {
        #pragma unroll
        for (int r = 0; r < 4; ++r) {
            int R = lg * 4 + r;
            int d = db * 16 + lr;
            Og[obase + (long)R * 64 + d] = o[db][r] * inv[r];
        }
    }
}

extern "C" void kernel_launch(void* const* d_in, const int* in_sizes, int n_in,
                              void* d_out, int out_size, void* d_ws, size_t ws_size,
                              hipStream_t stream) {
    const float* query = (const float*)d_in[0];
    const float* key   = (const float*)d_in[1];
    const float* value = (const float*)d_in[2];
    const float* Wq    = (const float*)d_in[3];
    const float* bq    = (const float*)d_in[4];
    const float* Wk    = (const float*)d_in[5];
    const float* bk    = (const float*)d_in[6];
    const float* Wv    = (const float*)d_in[7];
    const float* bv    = (const float*)d_in[8];

    const size_t elems = (size_t)B_ * H_ * S_ * D_;
    _Float16* qws  = (_Float16*)d_ws;
    _Float16* kws  = qws + elems;
    _Float16* vws  = kws + elems;
    _Float16* vtws = vws + elems;   // [B,H,D,S]

    proj_kernel<<<dim3(S_ / 64, B_ * H_, 3), 256, 0, stream>>>(
        query, key, value, Wq, bq, Wk, bk, Wv, bv, qws, kws, vws);

    transpose_v<<<dim3(S_ / 64, B_ * H_), 256, 0, stream>>>(vws, vtws);

    attn_kernel<<<dim3(B_ * H_, S_ / QBLK), 256, 0, stream>>>(
        qws, kws, vtws, (float*)d_out);
}